// Round 1
// baseline (2269.109 us; speedup 1.0000x reference)
//
#include <hip/hip_runtime.h>
#include <hip/hip_bf16.h>

#define B_   8
#define C_   512
#define H_   128
#define W_   128
#define CQ_  64
#define BH_  (B_ * H_)
#define HW_  (H_ * W_)

__device__ __forceinline__ float bflo(unsigned int u) {
    union { unsigned int i; float f; } v; v.i = u << 16; return v.f;
}
__device__ __forceinline__ float bfhi(unsigned int u) {
    union { unsigned int i; float f; } v; v.i = u & 0xffff0000u; return v.f;
}

// ---------------------------------------------------------------------------
// K1: q,k conv1x1.  grid = BH (1024), block = 256.
// q[bh][o][w], k[bh][o][w] fp32 -> scratch (in d_out).
// ---------------------------------------------------------------------------
__global__ __launch_bounds__(256) void qk_kernel(
    const float* __restrict__ x, const float* __restrict__ Wq,
    const float* __restrict__ bq, const float* __restrict__ Wk,
    const float* __restrict__ bk, float* __restrict__ qout,
    float* __restrict__ kout) {
  __shared__ __align__(16) float xs[32 * 128];   // [cc][w]
  __shared__ float wqs[64 * 33];                 // [o][cc] pad 33
  __shared__ float wks[64 * 33];
  const int t  = threadIdx.x;
  const int bh = blockIdx.x;
  const int b  = bh >> 7, h = bh & 127;
  const int wg = t & 7, og = t >> 3;             // wg: w-group (16 w), og: o-pair
  const float* xbase = x + (size_t)b * C_ * HW_ + (size_t)h * W_;

  float qa0[16], qa1[16], ka0[16], ka1[16];
#pragma unroll
  for (int m = 0; m < 16; ++m) { qa0[m] = 0.f; qa1[m] = 0.f; ka0[m] = 0.f; ka1[m] = 0.f; }

  for (int ctile = 0; ctile < 16; ++ctile) {
    const int cbase = ctile * 32;
    __syncthreads();
#pragma unroll
    for (int s = 0; s < 16; ++s) {
      int e = t + s * 256; int cc = e >> 7, w = e & 127;
      xs[e] = xbase[(size_t)(cbase + cc) * HW_ + w];
    }
#pragma unroll
    for (int s = 0; s < 8; ++s) {
      int e = t + s * 256; int o = e >> 5, cc = e & 31;
      wqs[o * 33 + cc] = Wq[o * C_ + cbase + cc];
      wks[o * 33 + cc] = Wk[o * C_ + cbase + cc];
    }
    __syncthreads();
#pragma unroll 8
    for (int cc = 0; cc < 32; ++cc) {
      const float4* xr = (const float4*)(xs + cc * 128 + wg * 16);
      float xv[16];
      *(float4*)&xv[0]  = xr[0];
      *(float4*)&xv[4]  = xr[1];
      *(float4*)&xv[8]  = xr[2];
      *(float4*)&xv[12] = xr[3];
      const float wq0 = wqs[(og * 2 + 0) * 33 + cc];
      const float wq1 = wqs[(og * 2 + 1) * 33 + cc];
      const float wk0 = wks[(og * 2 + 0) * 33 + cc];
      const float wk1 = wks[(og * 2 + 1) * 33 + cc];
#pragma unroll
      for (int m = 0; m < 16; ++m) {
        qa0[m] = fmaf(wq0, xv[m], qa0[m]);
        qa1[m] = fmaf(wq1, xv[m], qa1[m]);
        ka0[m] = fmaf(wk0, xv[m], ka0[m]);
        ka1[m] = fmaf(wk1, xv[m], ka1[m]);
      }
    }
  }

  const int o0 = og * 2, o1 = og * 2 + 1;
  const float bq0 = bq[o0], bq1 = bq[o1], bk0 = bk[o0], bk1 = bk[o1];
  float* q0 = qout + (size_t)bh * CQ_ * W_ + o0 * W_ + wg * 16;
  float* q1 = qout + (size_t)bh * CQ_ * W_ + o1 * W_ + wg * 16;
  float* k0 = kout + (size_t)bh * CQ_ * W_ + o0 * W_ + wg * 16;
  float* k1 = kout + (size_t)bh * CQ_ * W_ + o1 * W_ + wg * 16;
#pragma unroll
  for (int m = 0; m < 16; ++m) {
    q0[m] = qa0[m] + bq0;
    q1[m] = qa1[m] + bq1;
    k0[m] = ka0[m] + bk0;
    k1[m] = ka1[m] + bk1;
  }
}

// ---------------------------------------------------------------------------
// K2: energy + softmax.  grid = BH, block = 256 (4 waves, 32 rows each).
// energy[i][j] = sum_c q[i>>1][(i&1)*64+c] * k[j&63][2c+(j>>6)]
// attn fp32 -> d_ws.
// ---------------------------------------------------------------------------
__global__ __launch_bounds__(256) void attn_kernel(
    const float* __restrict__ qin, const float* __restrict__ kin,
    float* __restrict__ attn) {
  __shared__ float qs[64 * 128];   // [cq][w]
  __shared__ float kts[128 * 64];  // [w][cq] (transposed)
  const int t  = threadIdx.x;
  const int bh = blockIdx.x;
  const int lane = t & 63, wv = t >> 6;
  const float* qb = qin + (size_t)bh * 8192;
  const float* kb = kin + (size_t)bh * 8192;
#pragma unroll
  for (int s = 0; s < 32; ++s) {
    int e = t + s * 256;
    qs[e] = qb[e];
    int cq = e >> 7, w = e & 127;
    kts[w * 64 + cq] = kb[e];
  }
  __syncthreads();
  float* arow = attn + (size_t)bh * 16384;
  for (int r = 0; r < 32; ++r) {
    const int i = wv * 32 + r;
    const float* qrow = &qs[(i >> 1) * 128 + ((i & 1) << 6)];
    float elo = 0.f, ehi = 0.f;
#pragma unroll 16
    for (int c = 0; c < 64; ++c) {
      const float qv = qrow[c];
      elo = fmaf(qv, kts[(2 * c) * 64 + lane], elo);
      ehi = fmaf(qv, kts[(2 * c + 1) * 64 + lane], ehi);
    }
    float m = fmaxf(elo, ehi);
#pragma unroll
    for (int off = 32; off; off >>= 1) m = fmaxf(m, __shfl_xor(m, off));
    const float plo = __expf(elo - m), phi = __expf(ehi - m);
    float ssum = plo + phi;
#pragma unroll
    for (int off = 32; off; off >>= 1) ssum += __shfl_xor(ssum, off);
    const float inv = 1.0f / ssum;
    arow[i * 128 + lane]      = plo * inv;
    arow[i * 128 + 64 + lane] = phi * inv;
  }
}

// ---------------------------------------------------------------------------
// K3: v conv1x1 tile + PV + epilogue.  grid = BH*8 (c-tiles of 64), block=256.
// out[b][ct*64+c'][h][i] = gamma * sum_j attn[i][j] * v[c'][j] + x[...]
// ---------------------------------------------------------------------------
__global__ __launch_bounds__(256) void out_kernel(
    const float* __restrict__ x, const float* __restrict__ Wv,
    const float* __restrict__ bv, const float* __restrict__ attn,
    const float* __restrict__ gamma, float* __restrict__ out) {
  // byte layout: [0,16384) xs | [16384,20736) wvs || later [0,34816) attnT
  //              [34816, 51712) vT
  __shared__ __align__(16) float smemf[12928];  // 51712 bytes
  float* xs = smemf;                                             // [32][128]
  __hip_bfloat16* wvs   = (__hip_bfloat16*)(smemf + 4096);       // [64][34]
  __hip_bfloat16* attnT = (__hip_bfloat16*)smemf;                // [j:128][i:136]
  __hip_bfloat16* vT    = (__hip_bfloat16*)((char*)smemf + 34816); // [j:128][c':66]

  const int t  = threadIdx.x;
  const int bh = blockIdx.x >> 3, ct = blockIdx.x & 7;
  const int b  = bh >> 7, h = bh & 127;
  const int wg = t & 7, og = t >> 3;
  const float* xbase = x + (size_t)b * C_ * HW_ + (size_t)h * W_;

  // ---- phase A: v[c'][j] for c' in [ct*64, ct*64+64), j in [0,128) ----
  float va0[16], va1[16];
#pragma unroll
  for (int m = 0; m < 16; ++m) { va0[m] = 0.f; va1[m] = 0.f; }

  for (int ctile = 0; ctile < 16; ++ctile) {
    const int cbase = ctile * 32;
    __syncthreads();
#pragma unroll
    for (int s = 0; s < 16; ++s) {
      int e = t + s * 256; int cc = e >> 7, w = e & 127;
      xs[e] = xbase[(size_t)(cbase + cc) * HW_ + w];
    }
#pragma unroll
    for (int s = 0; s < 8; ++s) {
      int e = t + s * 256; int row = e >> 5, cc = e & 31;
      wvs[row * 34 + cc] = __float2bfloat16(Wv[(size_t)(ct * 64 + row) * C_ + cbase + cc]);
    }
    __syncthreads();
#pragma unroll 8
    for (int cc = 0; cc < 32; ++cc) {
      const float4* xr = (const float4*)(xs + cc * 128 + wg * 16);
      float xv[16];
      *(float4*)&xv[0]  = xr[0];
      *(float4*)&xv[4]  = xr[1];
      *(float4*)&xv[8]  = xr[2];
      *(float4*)&xv[12] = xr[3];
      const float w0 = __bfloat162float(wvs[(og * 2 + 0) * 34 + cc]);
      const float w1 = __bfloat162float(wvs[(og * 2 + 1) * 34 + cc]);
#pragma unroll
      for (int m = 0; m < 16; ++m) {
        va0[m] = fmaf(w0, xv[m], va0[m]);
        va1[m] = fmaf(w1, xv[m], va1[m]);
      }
    }
  }
  __syncthreads();  // all phase-A LDS reads done

  // store vT (vT does not overlap xs/wvs)
  {
    const float bv0 = bv[ct * 64 + og * 2];
    const float bv1 = bv[ct * 64 + og * 2 + 1];
#pragma unroll
    for (int m = 0; m < 16; ++m) {
      const int j = wg * 16 + m;
      vT[j * 66 + og * 2]     = __float2bfloat16(va0[m] + bv0);
      vT[j * 66 + og * 2 + 1] = __float2bfloat16(va1[m] + bv1);
    }
  }
  // stage attn transposed (overwrites xs/wvs region)
  const float* ab = attn + (size_t)bh * 16384;
#pragma unroll
  for (int s = 0; s < 64; ++s) {
    int e = t + s * 256; int i = e >> 7, j = e & 127;
    attnT[j * 136 + i] = __float2bfloat16(ab[e]);
  }
  __syncthreads();

  // ---- phase B: out[i][c'] = sum_j attn[i][j] * v[c'][j] ----
  const int lane = t & 63, wvv = t >> 6, i0 = wvv * 32;
  float acc[32];
#pragma unroll
  for (int r = 0; r < 32; ++r) acc[r] = 0.f;

  for (int j = 0; j < 128; ++j) {
    const float vv = __bfloat162float(vT[j * 66 + lane]);
    const uint4* ap = (const uint4*)(attnT + j * 136 + i0);
    unsigned int pw[16];
    *(uint4*)&pw[0]  = ap[0];
    *(uint4*)&pw[4]  = ap[1];
    *(uint4*)&pw[8]  = ap[2];
    *(uint4*)&pw[12] = ap[3];
#pragma unroll
    for (int u = 0; u < 16; ++u) {
      acc[2 * u]     = fmaf(bflo(pw[u]), vv, acc[2 * u]);
      acc[2 * u + 1] = fmaf(bfhi(pw[u]), vv, acc[2 * u + 1]);
    }
  }

  const float g = gamma[0];
  const size_t obase = ((size_t)b * C_ + ct * 64 + lane) * HW_ + (size_t)h * W_ + i0;
  const float* xr = x + obase;
  float* orow = out + obase;
#pragma unroll
  for (int r = 0; r < 32; ++r) orow[r] = fmaf(g, acc[r], xr[r]);
}

// ---------------------------------------------------------------------------
extern "C" void kernel_launch(void* const* d_in, const int* in_sizes, int n_in,
                              void* d_out, int out_size, void* d_ws, size_t ws_size,
                              hipStream_t stream) {
  const float* x     = (const float*)d_in[0];
  const float* Wq    = (const float*)d_in[1];
  const float* bq    = (const float*)d_in[2];
  const float* Wk    = (const float*)d_in[3];
  const float* bk    = (const float*)d_in[4];
  const float* Wv    = (const float*)d_in[5];
  const float* bv    = (const float*)d_in[6];
  const float* gamma = (const float*)d_in[7];
  float* out = (float*)d_out;

  // q,k scratch inside d_out (16.8M floats of 67.1M); K3 overwrites everything.
  float* qbuf = out;
  float* kbuf = out + (size_t)BH_ * CQ_ * W_;
  float* attn = (float*)d_ws;  // 64 MiB

  qk_kernel<<<BH_, 256, 0, stream>>>(x, Wq, bq, Wk, bk, qbuf, kbuf);
  attn_kernel<<<BH_, 256, 0, stream>>>(qbuf, kbuf, attn);
  out_kernel<<<BH_ * 8, 256, 0, stream>>>(x, Wv, bv, attn, gamma, out);
}